// Round 1
// baseline (67.594 us; speedup 1.0000x reference)
//
#include <hip/hip_runtime.h>

#define HW_   50176      // 224*224
#define QHW_  12544      // HW_/4
#define NIMG_ 64
#define PSTR_ 196608     // 64*32*32*3 floats per image

__device__ __forceinline__ float fpow(float x, float e) {
    // x > 0 guaranteed by callers; v_log_f32 is log2, v_exp_f32 is exp2
    return __builtin_amdgcn_exp2f(e * __builtin_amdgcn_logf(x));
}

__device__ __forceinline__ float srgb_lin(float c) {
    // mask blend in ref is equivalent to ternary (both branches finite)
    return c < 0.04045f ? c * (1.0f / 12.92f)
                        : fpow((c + 0.055f) * (1.0f / 1.055f), 2.4f);
}

__device__ __forceinline__ float enc_srgb(float c) {
    float e = (c < 0.0031308f)
                  ? 12.92f * c
                  : 1.055f * fpow(fmaxf(c, 1e-10f), 1.0f / 2.4f) - 0.055f;
    return fminf(fmaxf(e, 0.0f), 1.0f);
}

__global__ __launch_bounds__(256) void cieluv_kernel(
    const float* __restrict__ imgs,
    const float* __restrict__ params,
    float* __restrict__ out)
{
    // XCD-chunk swizzle (bijective: gridDim.x=3136 divisible by 8):
    // XCD k gets contiguous block range -> per-image params stay L2-resident.
    int bid = blockIdx.x;
    int cpx = gridDim.x >> 3;                 // 392
    int b   = (bid & 7) * cpx + (bid >> 3);

    int vi = b * 256 + threadIdx.x;           // vector-of-4-pixels index
    int n  = vi / QHW_;                       // image
    int pv = (vi - n * QHW_) * 4;             // pixel offset within plane

    const float* img = imgs + (size_t)n * (3 * HW_) + pv;
    float4 rv = *(const float4*)(img);
    float4 gv = *(const float4*)(img + HW_);
    float4 bv = *(const float4*)(img + 2 * HW_);
    const float* __restrict__ plist = params + (size_t)n * PSTR_;

    float Rr[4] = {rv.x, rv.y, rv.z, rv.w};
    float Gg[4] = {gv.x, gv.y, gv.z, gv.w};
    float Bb[4] = {bv.x, bv.y, bv.z, bv.w};
    float O0[4], O1[4], O2[4];

#pragma unroll
    for (int i = 0; i < 4; ++i) {
        // ---- sRGB -> linear ----
        float r = srgb_lin(Rr[i]);
        float g = srgb_lin(Gg[i]);
        float bl = srgb_lin(Bb[i]);
        // ---- linear RGB -> XYZ ----
        float x = 0.4124f * r + 0.3576f * g + 0.1805f * bl;
        float y = 0.2126f * r + 0.7152f * g + 0.0722f * bl;
        float z = 0.0193f * r + 0.1192f * g + 0.9504f * bl;
        // ---- XYZ -> LUV (normalized) ----
        float inv = 1.0f / (x + 15.0f * y + 3.0f * z + 1e-10f);
        float up = 4.0f * x * inv;
        float vp = 9.0f * y * inv;
        float L = (y < 0.008856451679035631f)
                      ? 903.2962962962963f * y
                      : 116.0f * fpow(fmaxf(y, 1e-10f), 1.0f / 3.0f) - 16.0f;
        float u = 13.0f * L * (up - 0.1978f);
        float v = 13.0f * L * (vp - 0.4683f);
        float c0 = L * 0.01f;
        float c1 = (u + 100.0f) * 0.005f;
        float c2 = (v + 100.0f) * 0.005f;
        // ---- trilinear LUT (RX=64, RY=32, RZ=32) ----
        float s0 = c0 * 63.0f, s1 = c1 * 31.0f, s2 = c2 * 31.0f;
        float f0 = floorf(s0), f1 = floorf(s1), f2 = floorf(s2);
        float w1x = s0 - f0, w1y = s1 - f1, w1z = s2 - f2;   // == s % 1
        float w0x = 1.0f - w1x, w0y = 1.0f - w1y, w0z = 1.0f - w1z;
        int i0 = (int)f0, i1 = (int)f1, i2 = (int)f2;
        int ix0 = min(max(i0, 0), 63), ix1 = min(max(i0 + 1, 0), 63);
        int iy0 = min(max(i1, 0), 31), iy1 = min(max(i1 + 1, 0), 31);
        int iz0 = min(max(i2, 0), 31), iz1 = min(max(i2 + 1, 0), 31);
        int bx0 = ix0 << 10, bx1 = ix1 << 10;
        int by0 = iy0 << 5,  by1 = iy1 << 5;

        float a0 = 0.0f, a1 = 0.0f, a2 = 0.0f;
        {
            const float* p; float w;
            p = plist + (bx0 + by0 + iz0) * 3; w = w0x * w0y * w0z;
            a0 += p[0] * w; a1 += p[1] * w; a2 += p[2] * w;
            p = plist + (bx0 + by0 + iz1) * 3; w = w0x * w0y * w1z;
            a0 += p[0] * w; a1 += p[1] * w; a2 += p[2] * w;
            p = plist + (bx0 + by1 + iz0) * 3; w = w0x * w1y * w0z;
            a0 += p[0] * w; a1 += p[1] * w; a2 += p[2] * w;
            p = plist + (bx0 + by1 + iz1) * 3; w = w0x * w1y * w1z;
            a0 += p[0] * w; a1 += p[1] * w; a2 += p[2] * w;
            p = plist + (bx1 + by0 + iz0) * 3; w = w1x * w0y * w0z;
            a0 += p[0] * w; a1 += p[1] * w; a2 += p[2] * w;
            p = plist + (bx1 + by0 + iz1) * 3; w = w1x * w0y * w1z;
            a0 += p[0] * w; a1 += p[1] * w; a2 += p[2] * w;
            p = plist + (bx1 + by1 + iz0) * 3; w = w1x * w1y * w0z;
            a0 += p[0] * w; a1 += p[1] * w; a2 += p[2] * w;
            p = plist + (bx1 + by1 + iz1) * 3; w = w1x * w1y * w1z;
            a0 += p[0] * w; a1 += p[1] * w; a2 += p[2] * w;
        }
        a0 = fminf(fmaxf(a0, 0.0f), 1.0f);
        a1 = fminf(fmaxf(a1, 0.0f), 1.0f);
        a2 = fminf(fmaxf(a2, 0.0f), 1.0f);
        // ---- LUV -> XYZ ----
        float L2 = a0 * 100.0f;
        float uu = a1 * 200.0f - 100.0f;
        float vv = a2 * 200.0f - 100.0f;
        float idl = 1.0f / (13.0f * L2 + 1e-10f);
        float up2 = uu * idl + 0.1978f;
        float vp2 = vv * idl + 0.4683f;
        float y2;
        if (L2 <= 8.0f) {
            y2 = L2 * 0.0011070564598794539f;       // (3/29)^3
        } else {
            float t = (L2 + 16.0f) * (1.0f / 116.0f);
            y2 = t * t * t;
        }
        float dn = 4.0f * vp2 + 1e-10f;
        float x2 = y2 * 9.0f * up2 / dn;
        float z2 = y2 * (12.0f - 3.0f * up2 - 20.0f * vp2) / dn;
        x2 = fminf(fmaxf(x2, 0.0f), 1.1f);
        float y2c = fminf(fmaxf(y2, 0.0f), 1.1f);
        z2 = fminf(fmaxf(z2, 0.0f), 1.1f);
        // ---- XYZ -> sRGB ----
        float rr = 3.2406f * x2 - 1.5372f * y2c - 0.4986f * z2;
        float gg = -0.9689f * x2 + 1.8758f * y2c + 0.0415f * z2;
        float b2 = 0.0557f * x2 - 0.2040f * y2c + 1.0570f * z2;
        O0[i] = enc_srgb(rr);
        O1[i] = enc_srgb(gg);
        O2[i] = enc_srgb(b2);
    }

    float* o = out + (size_t)n * (3 * HW_) + pv;
    *(float4*)(o)           = make_float4(O0[0], O0[1], O0[2], O0[3]);
    *(float4*)(o + HW_)     = make_float4(O1[0], O1[1], O1[2], O1[3]);
    *(float4*)(o + 2 * HW_) = make_float4(O2[0], O2[1], O2[2], O2[3]);
}

extern "C" void kernel_launch(void* const* d_in, const int* in_sizes, int n_in,
                              void* d_out, int out_size, void* d_ws, size_t ws_size,
                              hipStream_t stream) {
    const float* imgs   = (const float*)d_in[0];   // (64,3,224,224) f32
    const float* params = (const float*)d_in[1];   // (64,64,32,32,3) f32
    float* out = (float*)d_out;                    // (64,3,224,224) f32
    // 64 images * 12544 vec4/image = 802816 threads = 3136 blocks * 256
    cieluv_kernel<<<dim3(3136), dim3(256), 0, stream>>>(imgs, params, out);
}